// Round 9
// baseline (17.103 us; speedup 1.0000x reference)
//
#include <hip/hip_runtime.h>
#include <math.h>

// HippoSSKernel (S4 SSKernelDiag forward, ZOH): K[h,l] = 2*Re(sum_n Cw[h,n]*exp(dtA[h,n]*l))
// H=1024, N=64, CH=1, L=2048.
//
// R9: 4 waves/SIMD (16 waves/CU) at constant instruction count.
// TPB=1024, 4 heads/block (256 threads = 4 waves per head), LPT=8, q=b^256.
// Thread (head s, wave w, lane) owns l = lane + 64*w + 256*j, j<8.
// Per-wave seed constant hw = Cw2*b^(64w) (so the 64-entry b^i table is shared
// by all 4 waves). Chebyshev: u_{j+1} = 2Re(q) u_j - |q|^2 u_{j-1}, packed f32
// over (even n, odd n) pairs. Per pair: 3 LDS reads (T b128 per-lane + HW b128
// bcast + Q b128 bcast) + 29 pk-inst for 16 terms. grid=256 -> 1 block/CU,
// LDS 143 KB, __launch_bounds__(1024,4) pins VGPR<=128 for 4 waves/SIMD.

#define HH   1024
#define NN   64
#define LLEN 2048
#define TPB  1024
#define HPB  4                 // heads per block
#define LPT  8                 // terms per thread
#define NP   (NN / 2)          // 32 n-pairs

typedef float v2f __attribute__((ext_vector_type(2)));
typedef float v4f __attribute__((ext_vector_type(4)));

__device__ __forceinline__ float2 cmul(float2 a, float2 b) {
    return make_float2(fmaf(a.x, b.x, -(a.y * b.y)),
                       fmaf(a.x, b.y,   a.y * b.x));
}

__device__ __forceinline__ v2f vfma(v2f a, v2f b, v2f c) {
    return __builtin_elementwise_fma(a, b, c);
}

__global__ __launch_bounds__(TPB, 4) void sskernel_diag(
    const float* __restrict__ log_dt,      // (H,)
    const float* __restrict__ log_w_real,  // (H,N)
    const float* __restrict__ w_imag,      // (H,N)
    const float* __restrict__ C_re,        // (1,H,N)
    const float* __restrict__ C_im,        // (1,H,N)
    float* __restrict__ out)               // (1,H,L)
{
    // [s][p][i] = {xe, xo, ye, yo} of b^i for pair p; row pad 65 keeps the
    // scattered fill writes at 4-way (vs 16-way unpadded); reads are per-lane
    // consecutive b128 (conflict-free).
    __shared__ v4f s_T[HPB][NP][NN + 1];   // 4*32*65*16 = 133120 B
    __shared__ v4f s_HW[HPB][4][NP];       // {hx_e,hx_o,hy_e,hy_o} per (w,p): 8192 B
    __shared__ v4f s_AM[HPB][NP];          // {qx_e,qx_o,qy_e,qy_o}: 2048 B

    const int t    = threadIdx.x;
    const int s    = t >> 8;               // head within block (0..3)
    const int tid  = t & 255;              // thread within head
    const int w    = (t >> 6) & 3;         // wave within head (0..3)
    const int lane = t & 63;
    const int h    = blockIdx.x * HPB + s;

    // ---- Prologue: thread (h, w, lane) computes n = lane's parameters ----
    const int n   = lane;
    const int p   = n >> 1;
    const int sl  = n & 1;                 // slot within pair
    const int idx = h * NN + n;
    const float dtv = __expf(log_dt[h]);
    const float wr  = -__expf(log_w_real[idx]);
    const float wi  = w_imag[idx];
    const float dar = wr * dtv;
    const float dai = wi * dtv;

    const float em = __expf(dar);
    float sv, cv;
    __sincosf(dai, &sv, &cv);
    const float2 b = make_float2(em * cv, em * sv);     // exp(dtA)

    // Cw2 = 2 * C * (b - 1) / w   (final factor of 2 folded in)
    const float numr = b.x - 1.0f;
    const float numi = b.y;
    const float inv  = 2.0f / (wr * wr + wi * wi);
    const float tr = (numr * wr + numi * wi) * inv;
    const float ti = (numi * wr - numr * wi) * inv;
    const float cr = C_re[idx];
    const float ci = C_im[idx];
    const float2 Cw2 = make_float2(cr * tr - ci * ti, cr * ti + ci * tr);

    // squaring chain to q = b^256
    const float2 q1 = cmul(b,  b);
    const float2 q2 = cmul(q1, q1);
    const float2 q3 = cmul(q2, q2);
    const float2 q4 = cmul(q3, q3);   // b^16
    const float2 q5 = cmul(q4, q4);   // b^32
    const float2 q6 = cmul(q5, q5);   // b^64
    const float2 q7 = cmul(q6, q6);   // b^128
    const float2 q8 = cmul(q7, q7);   // q = b^256

    // hw = Cw2 * b^(64*w) for THIS wave
    float2 hw = Cw2;
    if (w & 1) hw = cmul(hw, q6);
    if (w & 2) hw = cmul(hw, q7);
    {
        float* f = (float*)&s_HW[s][w][p];
        f[sl] = hw.x; f[2 + sl] = hw.y;
    }
    if (w == 0) {
        float* f = (float*)&s_AM[s][p];
        f[sl] = q8.x; f[2 + sl] = q8.y;
    }

    // cooperative fill: wave w fills i in [16w, 16w+16), 16 cmul/thread
    float2 e = make_float2(1.0f, 0.0f);
    if (w & 1) e = cmul(e, q4);       // b^16
    if (w & 2) e = cmul(e, q5);       // b^32 (w=3 -> b^48)
#pragma unroll
    for (int i = 0; i < 16; ++i) {
        float* f = (float*)&s_T[s][p][16 * w + i];
        f[sl] = e.x; f[2 + sl] = e.y;
        e = cmul(e, b);
    }
    __syncthreads();

    // ---- Main loop: 3 LDS reads + 29 pk-inst per n-pair (16 terms) ----
    v2f acc[LPT] = {};

#pragma unroll 8
    for (int pp = 0; pp < NP; ++pp) {
        const v4f T  = s_T[s][pp][lane];    // {xe,xo,ye,yo} = b^lane
        const v4f HW = s_HW[s][w][pp];      // uniform -> broadcast
        const v4f Q  = s_AM[s][pp];         // uniform -> broadcast

        const v2f Tx = {T.x, T.y},  Ty = {T.z, T.w};
        const v2f hx = {HW.x, HW.y}, hy = {HW.z, HW.w};
        const v2f qx = {Q.x, Q.y},  qy = {Q.z, Q.w};

        const v2f zx = vfma(Tx, hx, -(Ty * hy));      // Re(hw * b^lane)
        const v2f zy = vfma(Tx, hy,   Ty * hx);       // Im(hw * b^lane)
        const v2f an = qx + qx;                       // 2 Re(q)
        const v2f m  = vfma(qx, qx, qy * qy);         // |q|^2
        v2f u0 = zx;
        v2f u1 = vfma(zx, qx, -(zy * qy));            // Re(z*q)
        acc[0] += u0;
        acc[1] += u1;
#pragma unroll
        for (int j = 2; j < LPT; ++j) {
            const v2f u = vfma(an, u1, -(m * u0));    // packed Chebyshev step
            acc[j] += u;
            u0 = u1;
            u1 = u;
        }
    }

    // ---- Epilogue: coalesced stores (2x folded into Cw2) ----
    float* o = out + (size_t)h * LLEN;
#pragma unroll
    for (int j = 0; j < LPT; ++j)
        o[tid + j * 256] = acc[j].x + acc[j].y;
}

extern "C" void kernel_launch(void* const* d_in, const int* in_sizes, int n_in,
                              void* d_out, int out_size, void* d_ws, size_t ws_size,
                              hipStream_t stream) {
    const float* log_dt     = (const float*)d_in[0];
    const float* log_w_real = (const float*)d_in[1];
    const float* w_imag     = (const float*)d_in[2];
    const float* C_re       = (const float*)d_in[3];
    const float* C_im       = (const float*)d_in[4];
    float* out = (float*)d_out;

    sskernel_diag<<<HH / HPB, TPB, 0, stream>>>(log_dt, log_w_real, w_imag, C_re, C_im, out);
}

// Round 10
// 13.372 us; speedup vs baseline: 1.2790x; 1.2790x over previous
//
#include <hip/hip_runtime.h>
#include <math.h>

// HippoSSKernel (S4 SSKernelDiag forward, ZOH): K[h,l] = 2*Re(sum_n Cw[h,n]*exp(dtA[h,n]*l))
// H=1024, N=64, CH=1, L=2048.
//
// R10: MFMA reformulation. l = i + 64*j (i<64, j<32):
//   K[i+64j] = sum_n Re( A[i,n] * B[n,j] ),  A = Cw2*b^i (64x64), B = (b^64)^j (64x32)
// Two real GEMMs on the matrix pipe: Re = Ar*Br + (-Ai)*Bi. fp16 hi/lo split
// (hihi + hilo + lohi, lo-planes pre-scaled 2^10) gives ~fp32 precision.
// One head per block (256 thr, 4 waves); wave w owns i-tile w. Output oriented
// D[j][i] (m=j, n=i) so stores are 64B-coalesced.
// A-gen: direct __expf + v_sin/v_cos (args <= 1260 rad: ok in fp32).
// B-gen: complex chain from Q=b^64 (args up to 4e4 rad would break direct sincos).
// LDS 53.8KB -> 3 blocks/CU.

#define HH   1024
#define NN   64
#define LLEN 2048
#define TPB  256
#define PAD  68    // fp16 elems per LDS row: 136B rows (8B-aligned, bank-spread)

typedef _Float16 f16;
typedef f16 f16x4 __attribute__((ext_vector_type(4)));
typedef f16 f16x8 __attribute__((ext_vector_type(8)));
typedef float f32x4 __attribute__((ext_vector_type(4)));

#define INV2PI 0.15915494309189535f
#define LOSC   1024.0f
#define ILOSC  0.0009765625f

__device__ __forceinline__ float2 cmul(float2 a, float2 b) {
    return make_float2(fmaf(a.x, b.x, -(a.y * b.y)),
                       fmaf(a.x, b.y,   a.y * b.x));
}

// sin/cos via hardware rev-unit ops with explicit fract reduction
__device__ __forceinline__ void sincos_rev(float rad, float* s, float* c) {
    float rev = __builtin_amdgcn_fractf(rad * INV2PI);
    *s = __builtin_amdgcn_sinf(rev);
    *c = __builtin_amdgcn_cosf(rev);
}

__device__ __forceinline__ f16x8 ld8(const f16* p) {
    f16x4 a = *(const f16x4*)p;        // ds_read_b64
    f16x4 b = *(const f16x4*)(p + 4);  // ds_read_b64
    return __builtin_shufflevector(a, b, 0, 1, 2, 3, 4, 5, 6, 7);
}

__global__ __launch_bounds__(TPB, 3) void sskernel_mfma(
    const float* __restrict__ log_dt,      // (H,)
    const float* __restrict__ log_w_real,  // (H,N)
    const float* __restrict__ w_imag,      // (H,N)
    const float* __restrict__ C_re,        // (1,H,N)
    const float* __restrict__ C_im,        // (1,H,N)
    float* __restrict__ out)               // (1,H,L)
{
    // A-side planes [i][n]: Ar = Re(Cw2*b^i), AN = -Im(Cw2*b^i); hi/lo fp16
    __shared__ f16 Arh[NN][PAD], Arl[NN][PAD], ANh[NN][PAD], ANl[NN][PAD];
    // B-side planes [j][n]: Br = Re((b^64)^j), Bi = Im; hi/lo fp16
    __shared__ f16 Brh[32][PAD], Brl[32][PAD], Bih[32][PAD], Bil[32][PAD];
    __shared__ float cDar[NN], cDai[NN], cCx[NN], cCy[NN], cQx[NN], cQy[NN];

    const int t    = threadIdx.x;
    const int h    = blockIdx.x;
    const int lane = t & 63;
    const int w    = t >> 6;             // wave index 0..3

    // ---- Phase 0: per-n constants (64 threads) ----
    if (t < NN) {
        const int n   = t;
        const int idx = h * NN + n;
        const float dtv = __expf(log_dt[h]);
        const float wr  = -__expf(log_w_real[idx]);
        const float wi  = w_imag[idx];
        const float dar = wr * dtv;
        const float dai = wi * dtv;

        const float em = __expf(dar);
        float sv, cv;
        sincos_rev(dai, &sv, &cv);
        const float2 b = make_float2(em * cv, em * sv);   // exp(dtA)

        // Cw2 = 2*C*(b-1)/w
        const float numr = b.x - 1.0f;
        const float numi = b.y;
        const float inv  = 2.0f / (wr * wr + wi * wi);
        const float tr = (numr * wr + numi * wi) * inv;
        const float ti = (numi * wr - numr * wi) * inv;
        const float cr = C_re[idx];
        const float ci = C_im[idx];

        // Q = b^64 by squaring (accurate chain)
        float2 q = b;
        q = cmul(q, q); q = cmul(q, q); q = cmul(q, q);
        q = cmul(q, q); q = cmul(q, q); q = cmul(q, q);

        cDar[n] = dar;
        cDai[n] = dai;
        cCx[n]  = cr * tr - ci * ti;
        cCy[n]  = cr * ti + ci * tr;
        cQx[n]  = q.x;
        cQy[n]  = q.y;
    }
    __syncthreads();

    // ---- Phase 1a: A-planes. thread -> (i = t>>2, n-strip 16*(t&3)) ----
    {
        const int i  = t >> 2;
        const int n0 = 16 * (t & 3);
        const float fi = (float)i;
#pragma unroll 4
        for (int kk = 0; kk < 16; ++kk) {
            const int n = n0 + kk;
            const float dar = cDar[n], dai = cDai[n];
            const float cx = cCx[n],  cy = cCy[n];
            const float em = __expf(dar * fi);
            float sv, cv;
            sincos_rev(dai * fi, &sv, &cv);
            const float zx = em * cv, zy = em * sv;
            const float ar =   fmaf(zx, cx, -(zy * cy));   //  Re(Cw2*b^i)
            const float an = -(fmaf(zx, cy,   zy * cx));   // -Im(Cw2*b^i)
            const f16 arh = (f16)ar;
            const f16 anh = (f16)an;
            Arh[i][n] = arh;
            ANh[i][n] = anh;
            Arl[i][n] = (f16)((ar - (float)arh) * LOSC);
            ANl[i][n] = (f16)((an - (float)anh) * LOSC);
        }
    }

    // ---- Phase 1b: B-planes by chain. thread -> (n = lane, j-strip 8*w) ----
    {
        const int n = lane;
        const float2 Q = make_float2(cQx[n], cQy[n]);
        const float2 Q2 = cmul(Q, Q);
        const float2 Q4 = cmul(Q2, Q2);
        const float2 Q8 = cmul(Q4, Q4);
        float2 e = make_float2(1.0f, 0.0f);
        if (w & 1) e = Q8;
        if (w & 2) e = cmul(e, cmul(Q8, Q8));
        const int js = 8 * w;
#pragma unroll
        for (int jj = 0; jj < 8; ++jj) {
            const int j = js + jj;
            const f16 bh = (f16)e.x;
            const f16 ih = (f16)e.y;
            Brh[j][n] = bh;
            Bih[j][n] = ih;
            Brl[j][n] = (f16)((e.x - (float)bh) * LOSC);
            Bil[j][n] = (f16)((e.y - (float)ih) * LOSC);
            e = cmul(e, Q);
        }
    }
    __syncthreads();

    // ---- Phase 2: GEMM. D[j][i] = sum_n Bmat[j][n]*Amat-as-[i][n].
    // MFMA m=j (A-port <- B-planes), n=i (B-port <- A-planes), k=n.
    // Both ports read the SAME 16B n-chunk per lane-group -> k-permutation-safe.
    const int r16 = lane & 15;
    const int g   = lane >> 4;

    f32x4 accH[2] = {{0,0,0,0},{0,0,0,0}};
    f32x4 accL[2] = {{0,0,0,0},{0,0,0,0}};

#pragma unroll
    for (int s = 0; s < 2; ++s) {
        const int c0 = 32 * s + 8 * g;
        // B-port operands (n_ = i side): wave w's i-tile rows
        const f16x8 xRh = ld8(&Arh[16 * w + r16][c0]);
        const f16x8 xRl = ld8(&Arl[16 * w + r16][c0]);
        const f16x8 xNh = ld8(&ANh[16 * w + r16][c0]);
        const f16x8 xNl = ld8(&ANl[16 * w + r16][c0]);
#pragma unroll
        for (int mt = 0; mt < 2; ++mt) {
            // A-port operands (m = j side)
            const f16x8 yRh = ld8(&Brh[16 * mt + r16][c0]);
            const f16x8 yRl = ld8(&Brl[16 * mt + r16][c0]);
            const f16x8 yIh = ld8(&Bih[16 * mt + r16][c0]);
            const f16x8 yIl = ld8(&Bil[16 * mt + r16][c0]);

            accH[mt] = __builtin_amdgcn_mfma_f32_16x16x32_f16(yRh, xRh, accH[mt], 0, 0, 0);
            accH[mt] = __builtin_amdgcn_mfma_f32_16x16x32_f16(yIh, xNh, accH[mt], 0, 0, 0);
            accL[mt] = __builtin_amdgcn_mfma_f32_16x16x32_f16(yRl, xRh, accL[mt], 0, 0, 0);
            accL[mt] = __builtin_amdgcn_mfma_f32_16x16x32_f16(yRh, xRl, accL[mt], 0, 0, 0);
            accL[mt] = __builtin_amdgcn_mfma_f32_16x16x32_f16(yIl, xNh, accL[mt], 0, 0, 0);
            accL[mt] = __builtin_amdgcn_mfma_f32_16x16x32_f16(yIh, xNl, accL[mt], 0, 0, 0);
        }
    }

    // ---- Epilogue: D row = j = 16*mt + 4*g + r, col = i = 16*w + r16 ----
    float* o = out + (size_t)h * LLEN;
#pragma unroll
    for (int mt = 0; mt < 2; ++mt) {
#pragma unroll
        for (int r = 0; r < 4; ++r) {
            const int j = 16 * mt + 4 * g + r;
            const int i = 16 * w + r16;
            o[i + 64 * j] = accH[mt][r] + accL[mt][r] * ILOSC;
        }
    }
}

extern "C" void kernel_launch(void* const* d_in, const int* in_sizes, int n_in,
                              void* d_out, int out_size, void* d_ws, size_t ws_size,
                              hipStream_t stream) {
    const float* log_dt     = (const float*)d_in[0];
    const float* log_w_real = (const float*)d_in[1];
    const float* w_imag     = (const float*)d_in[2];
    const float* C_re       = (const float*)d_in[3];
    const float* C_im       = (const float*)d_in[4];
    float* out = (float*)d_out;

    sskernel_mfma<<<HH, TPB, 0, stream>>>(log_dt, log_w_real, w_imag, C_re, C_im, out);
}

// Round 11
// 10.467 us; speedup vs baseline: 1.6340x; 1.2775x over previous
//
#include <hip/hip_runtime.h>
#include <math.h>

// HippoSSKernel (S4 SSKernelDiag forward, ZOH): K[h,l] = 2*Re(sum_n Cw[h,n]*exp(dtA[h,n]*l))
// H=1024, N=64, CH=1, L=2048.
//
// R11: MFMA formulation (l = i + 64j):
//   K[i+64j] = sum_n Re( A[i,n]*B[n,j] ),  A = Cw2*b^i, B = (b^64)^j
// Changes vs R10 (each targeting a measured/derived cost):
//  - A generated by 16-step COMPLEX CHAIN per (n=lane, wave=i-tile) from
//    phase-0 squaring seeds: removes all per-element exp/sincos and the
//    64 scattered const-reads per thread.
//  - fp16 HI-ONLY planes (no hi/lo split): absmax floor is the fp32-ref
//    comparison (constant 1.95e-3 across ALL rounds incl fp32 R1); fp16
//    quantization adds ~2-5e-3 << 32.7e-3 threshold. Halves LDS planes,
//    MFMA count 24->8, fragment reads 24->12.
//  - PAD=72 f16 (144B rows): fragment reads are single aligned ds_read_b128
//    at the 8-cyc bank floor (banks 4(r16+g)+16s cover all 32 evenly).
//  - LDS 30 KB -> 5 blocks/CU >= grid's 4/CU -> all 1024 blocks co-resident,
//    no dispatch tail (R10: 52.5 KB -> 3/CU, 256-block tail at 1/3 util).

#define HH   1024
#define NN   64
#define LLEN 2048
#define TPB  256
#define PAD  72

typedef _Float16 f16;
typedef f16 f16x8 __attribute__((ext_vector_type(8)));
typedef float f32x4 __attribute__((ext_vector_type(4)));

#define INV2PI 0.15915494309189535f

__device__ __forceinline__ float2 cmul(float2 a, float2 b) {
    return make_float2(fmaf(a.x, b.x, -(a.y * b.y)),
                       fmaf(a.x, b.y,   a.y * b.x));
}

__device__ __forceinline__ void sincos_rev(float rad, float* s, float* c) {
    float rev = __builtin_amdgcn_fractf(rad * INV2PI);
    *s = __builtin_amdgcn_sinf(rev);
    *c = __builtin_amdgcn_cosf(rev);
}

__global__ __launch_bounds__(TPB, 4) void sskernel_mfma(
    const float* __restrict__ log_dt,      // (H,)
    const float* __restrict__ log_w_real,  // (H,N)
    const float* __restrict__ w_imag,      // (H,N)
    const float* __restrict__ C_re,        // (1,H,N)
    const float* __restrict__ C_im,        // (1,H,N)
    float* __restrict__ out)               // (1,H,L)
{
    // fp16 planes, 144B rows (16B-aligned, even-bank-spread b128 reads)
    __shared__ __attribute__((aligned(16))) f16 Arh[NN][PAD];  //  Re(Cw2*b^i)
    __shared__ __attribute__((aligned(16))) f16 ANh[NN][PAD];  // -Im(Cw2*b^i)
    __shared__ __attribute__((aligned(16))) f16 Brh[32][PAD];  //  Re(Q^j)
    __shared__ __attribute__((aligned(16))) f16 Bih[32][PAD];  //  Im(Q^j)
    // per-n constants (separate arrays -> 2-way-free b64 reads at n=lane)
    __shared__ float2 cB[NN], cP16[NN], cP32[NN], cP48[NN], cC2[NN], cQ[NN];

    const int t    = threadIdx.x;
    const int h    = blockIdx.x;
    const int lane = t & 63;
    const int w    = t >> 6;             // wave index 0..3 (i-tile)

    // ---- Phase 0: per-n constants (64 threads) ----
    if (t < NN) {
        const int n   = t;
        const int idx = h * NN + n;
        const float dtv = __expf(log_dt[h]);
        const float wr  = -__expf(log_w_real[idx]);
        const float wi  = w_imag[idx];
        const float dar = wr * dtv;
        const float dai = wi * dtv;

        const float em = __expf(dar);
        float sv, cv;
        sincos_rev(dai, &sv, &cv);
        const float2 b = make_float2(em * cv, em * sv);   // exp(dtA)

        // Cw2 = 2*C*(b-1)/w
        const float numr = b.x - 1.0f;
        const float numi = b.y;
        const float inv  = 2.0f / (wr * wr + wi * wi);
        const float tr = (numr * wr + numi * wi) * inv;
        const float ti = (numi * wr - numr * wi) * inv;
        const float cr = C_re[idx];
        const float ci = C_im[idx];

        const float2 s1  = cmul(b,  b);     // b^2
        const float2 s2  = cmul(s1, s1);    // b^4
        const float2 s3  = cmul(s2, s2);    // b^8
        const float2 b16 = cmul(s3, s3);    // b^16
        const float2 b32 = cmul(b16, b16);  // b^32
        const float2 b48 = cmul(b32, b16);  // b^48
        const float2 Q   = cmul(b32, b32);  // b^64

        cB[n]   = b;
        cP16[n] = b16;
        cP32[n] = b32;
        cP48[n] = b48;
        cC2[n]  = make_float2(cr * tr - ci * ti, cr * ti + ci * tr);
        cQ[n]   = Q;
    }
    __syncthreads();

    // ---- Phase 1a: A planes by chain. thread (n=lane, w) -> i in [16w,16w+16) ----
    {
        const int n = lane;
        const float2 b = cB[n];
        float2 e = cC2[n];                 // Cw2 * b^(16w)
        if (w == 1) e = cmul(e, cP16[n]);
        if (w == 2) e = cmul(e, cP32[n]);
        if (w == 3) e = cmul(e, cP48[n]);
#pragma unroll
        for (int it = 0; it < 16; ++it) {
            const int i = 16 * w + it;
            Arh[i][n] = (f16)e.x;          // RTE converts
            ANh[i][n] = (f16)(-e.y);
            e = cmul(e, b);
        }
    }

    // ---- Phase 1b: B planes by chain. thread (n=lane, w) -> j in [8w,8w+8) ----
    {
        const int n = lane;
        const float2 Q  = cQ[n];
        const float2 q2 = cmul(Q,  Q);
        const float2 q4 = cmul(q2, q2);
        const float2 q8 = cmul(q4, q4);    // Q^8
        float2 e = make_float2(1.0f, 0.0f);
        if (w == 1) e = q8;
        if (w == 2) e = cmul(q8, q8);
        if (w == 3) e = cmul(cmul(q8, q8), q8);
#pragma unroll
        for (int jj = 0; jj < 8; ++jj) {
            const int j = 8 * w + jj;
            Brh[j][n] = (f16)e.x;
            Bih[j][n] = (f16)e.y;
            e = cmul(e, Q);
        }
    }
    __syncthreads();

    // ---- Phase 2: 12 b128 reads + 8 MFMA per wave ----
    // mfma_f32_16x16x32_f16: D[j-tile][i-tile], m=j (A-port<-B planes),
    // n=i (B-port<-A planes), k=n. Layout validated empirically in R10.
    const int r16 = lane & 15;
    const int g   = lane >> 4;

    f32x4 acc[2] = {{0,0,0,0},{0,0,0,0}};

#pragma unroll
    for (int s = 0; s < 2; ++s) {
        const int c0 = 32 * s + 8 * g;
        const f16x8 xR = *(const f16x8*)&Arh[16 * w + r16][c0];
        const f16x8 xN = *(const f16x8*)&ANh[16 * w + r16][c0];
#pragma unroll
        for (int mt = 0; mt < 2; ++mt) {
            const f16x8 yR = *(const f16x8*)&Brh[16 * mt + r16][c0];
            const f16x8 yI = *(const f16x8*)&Bih[16 * mt + r16][c0];
            acc[mt] = __builtin_amdgcn_mfma_f32_16x16x32_f16(yR, xR, acc[mt], 0, 0, 0);
            acc[mt] = __builtin_amdgcn_mfma_f32_16x16x32_f16(yI, xN, acc[mt], 0, 0, 0);
        }
    }

    // ---- Epilogue: D row j = 16mt+4g+r, col i = 16w+r16 ----
    float* o = out + (size_t)h * LLEN;
#pragma unroll
    for (int mt = 0; mt < 2; ++mt) {
#pragma unroll
        for (int r = 0; r < 4; ++r) {
            const int j = 16 * mt + 4 * g + r;
            const int i = 16 * w + r16;
            o[i + 64 * j] = acc[mt][r];
        }
    }
}

extern "C" void kernel_launch(void* const* d_in, const int* in_sizes, int n_in,
                              void* d_out, int out_size, void* d_ws, size_t ws_size,
                              hipStream_t stream) {
    const float* log_dt     = (const float*)d_in[0];
    const float* log_w_real = (const float*)d_in[1];
    const float* w_imag     = (const float*)d_in[2];
    const float* C_re       = (const float*)d_in[3];
    const float* C_im       = (const float*)d_in[4];
    float* out = (float*)d_out;

    sskernel_mfma<<<HH, TPB, 0, stream>>>(log_dt, log_w_real, w_imag, C_re, C_im, out);
}

// Round 12
// 10.457 us; speedup vs baseline: 1.6355x; 1.0010x over previous
//
#include <hip/hip_runtime.h>
#include <math.h>

// HippoSSKernel (S4 SSKernelDiag forward, ZOH): K[h,l] = 2*Re(sum_n Cw[h,n]*exp(dtA[h,n]*l))
// H=1024, N=64, CH=1, L=2048.
//
// R12 (consolidation): MFMA formulation, l = i + 64j:
//   K[i+64j] = sum_n ( Ar[i,n]Br[n,j] + AN[i,n]Bi[n,j] )
// expressed as ONE fp16 GEMM with k = 2n+phase (K=128): A'[i][2n]={Ar,AN},
// B'[j][2n]={Br,Bi}. Both MFMA ports read identical k-windows -> any HW
// k-permutation cancels (validated R10/R11).
// vs R11:
//  - phase 0 merged into all threads (4x redundant, transcendentals cheap):
//    kills 6 LDS const arrays + their traffic + ONE BARRIER.
//  - plane writes are packed b32 (half the write count of two b16 planes).
//  - LDS ~26 KB -> >=6 blocks/CU capacity (grid needs 4/CU; zero tail).
// Remaining ~9us is the measured launch/dispatch floor (invariant R6->R11).

#define HH   1024
#define NN   64
#define LLEN 2048
#define TPB  256
#define KW   128               // k-width in f16 (2*NN)
#define PAD  136               // f16 per row: 272B rows, 16B-aligned, 2-way banks

typedef _Float16 f16;
typedef f16 f16x8 __attribute__((ext_vector_type(8)));
typedef float f32x4 __attribute__((ext_vector_type(4)));

#define INV2PI 0.15915494309189535f

__device__ __forceinline__ float2 cmul(float2 a, float2 b) {
    return make_float2(fmaf(a.x, b.x, -(a.y * b.y)),
                       fmaf(a.x, b.y,   a.y * b.x));
}

__device__ __forceinline__ void sincos_rev(float rad, float* s, float* c) {
    float rev = __builtin_amdgcn_fractf(rad * INV2PI);
    *s = __builtin_amdgcn_sinf(rev);
    *c = __builtin_amdgcn_cosf(rev);
}

// pack two fp32 -> {f16, f16} as one 32-bit LDS store
__device__ __forceinline__ void pack_store(f16* p, float x, float y) {
    union { f16 h[2]; unsigned u; } v;
    v.h[0] = (f16)x;
    v.h[1] = (f16)y;
    *(unsigned*)p = v.u;
}

__global__ __launch_bounds__(TPB, 4) void sskernel_mfma(
    const float* __restrict__ log_dt,      // (H,)
    const float* __restrict__ log_w_real,  // (H,N)
    const float* __restrict__ w_imag,      // (H,N)
    const float* __restrict__ C_re,        // (1,H,N)
    const float* __restrict__ C_im,        // (1,H,N)
    float* __restrict__ out)               // (1,H,L)
{
    // k-interleaved planes: A'[i][2n]= Re(Cw2*b^i), A'[i][2n+1]= -Im(Cw2*b^i)
    //                       B'[j][2n]= Re(Q^j),     B'[j][2n+1]=  Im(Q^j)
    __shared__ __attribute__((aligned(16))) f16 Ap[NN][PAD];   // 17.4 KB
    __shared__ __attribute__((aligned(16))) f16 Bp[32][PAD];   //  8.7 KB

    const int t    = threadIdx.x;
    const int h    = blockIdx.x;
    const int lane = t & 63;
    const int w    = t >> 6;             // wave index 0..3 (i-tile)

    // ---- Phase 0 (all threads, redundant across waves): n = lane params ----
    const int n   = lane;
    const int idx = h * NN + n;
    const float dtv = __expf(log_dt[h]);
    const float wr  = -__expf(log_w_real[idx]);
    const float wi  = w_imag[idx];
    const float dar = wr * dtv;
    const float dai = wi * dtv;

    const float em = __expf(dar);
    float sv, cv;
    sincos_rev(dai, &sv, &cv);
    const float2 b = make_float2(em * cv, em * sv);   // exp(dtA)

    // Cw2 = 2*C*(b-1)/w
    const float numr = b.x - 1.0f;
    const float numi = b.y;
    const float inv  = 2.0f / (wr * wr + wi * wi);
    const float tr = (numr * wr + numi * wi) * inv;
    const float ti = (numi * wr - numr * wi) * inv;
    const float cr = C_re[idx];
    const float ci = C_im[idx];
    const float2 Cw2 = make_float2(cr * tr - ci * ti, cr * ti + ci * tr);

    const float2 s1  = cmul(b,  b);     // b^2
    const float2 s2  = cmul(s1, s1);    // b^4
    const float2 s3  = cmul(s2, s2);    // b^8
    const float2 b16 = cmul(s3, s3);    // b^16
    const float2 b32 = cmul(b16, b16);  // b^32
    const float2 Q   = cmul(b32, b32);  // b^64

    // ---- Phase 1a: A' rows by chain; wave w covers i in [16w, 16w+16) ----
    {
        float2 e = Cw2;                  // Cw2 * b^(16w)
        if (w == 1) e = cmul(e, b16);
        if (w == 2) e = cmul(e, b32);
        if (w == 3) e = cmul(e, cmul(b32, b16));
#pragma unroll
        for (int it = 0; it < 16; ++it) {
            pack_store(&Ap[16 * w + it][2 * n], e.x, -e.y);
            e = cmul(e, b);
        }
    }

    // ---- Phase 1b: B' rows by chain; wave w covers j in [8w, 8w+8) ----
    {
        const float2 q2 = cmul(Q,  Q);
        const float2 q4 = cmul(q2, q2);
        const float2 q8 = cmul(q4, q4);   // Q^8
        float2 e = make_float2(1.0f, 0.0f);
        if (w == 1) e = q8;
        if (w == 2) e = cmul(q8, q8);
        if (w == 3) e = cmul(cmul(q8, q8), q8);
#pragma unroll
        for (int jj = 0; jj < 8; ++jj) {
            pack_store(&Bp[8 * w + jj][2 * n], e.x, e.y);
            e = cmul(e, Q);
        }
    }
    __syncthreads();

    // ---- Phase 2: 12 b128 reads + 8 MFMA (K=128 over k=2n+phase) ----
    const int r16 = lane & 15;
    const int g   = lane >> 4;

    f32x4 acc[2] = {{0,0,0,0},{0,0,0,0}};

#pragma unroll
    for (int s = 0; s < 4; ++s) {
        const int c0 = 32 * s + 8 * g;                 // k-window (f16 units)
        const f16x8 x = *(const f16x8*)&Ap[16 * w + r16][c0];
#pragma unroll
        for (int mt = 0; mt < 2; ++mt) {
            const f16x8 y = *(const f16x8*)&Bp[16 * mt + r16][c0];
            acc[mt] = __builtin_amdgcn_mfma_f32_16x16x32_f16(y, x, acc[mt], 0, 0, 0);
        }
    }

    // ---- Epilogue: D row j = 16mt+4g+r, col i = 16w+r16 ----
    float* o = out + (size_t)h * LLEN;
#pragma unroll
    for (int mt = 0; mt < 2; ++mt) {
#pragma unroll
        for (int r = 0; r < 4; ++r) {
            const int j = 16 * mt + 4 * g + r;
            const int i = 16 * w + r16;
            o[i + 64 * j] = acc[mt][r];
        }
    }
}

extern "C" void kernel_launch(void* const* d_in, const int* in_sizes, int n_in,
                              void* d_out, int out_size, void* d_ws, size_t ws_size,
                              hipStream_t stream) {
    const float* log_dt     = (const float*)d_in[0];
    const float* log_w_real = (const float*)d_in[1];
    const float* w_imag     = (const float*)d_in[2];
    const float* C_re       = (const float*)d_in[3];
    const float* C_im       = (const float*)d_in[4];
    float* out = (float*)d_out;

    sskernel_mfma<<<HH, TPB, 0, stream>>>(log_dt, log_w_real, w_imag, C_re, C_im, out);
}